// Round 2
// baseline (176.476 us; speedup 1.0000x reference)
//
#include <hip/hip_runtime.h>
#include <hip/hip_bf16.h>

// Masked SDPA, flash-attention style, bf16 MFMA (16x16x32), fp32 accum.
// BZ=8, QL=KL=2048, D=128. Grid = 256 blocks (b*32 + qtile), block = 256 thr.
// Wave w owns q-rows [qtile*64 + 16w, +16). KV tiles of 64 keys staged in LDS.

#define BZ 8
#define QL 2048
#define KLEN 2048
#define DH 128
#define KT 64
#define NTILES (KLEN / KT)  // 32

#define KPITCH 136  // bf16 elems; 272B rows -> 2-way bank aliasing (free)
#define VPITCH 72   // bf16 elems; 144B rows
#define PPITCH 72

typedef float f32x4 __attribute__((ext_vector_type(4)));
typedef __bf16 bf16x8 __attribute__((ext_vector_type(8)));
typedef __bf16 bf16x4 __attribute__((ext_vector_type(4)));
typedef __bf16 bf16x2 __attribute__((ext_vector_type(2)));

// SCALE * log2(e): scores come out of QK^T already in log2 units.
#define QSC 0.12751879523298232f
#define NEGV -1000000000.0f

__global__ __launch_bounds__(256, 1) void fattn_kernel(
    const float* __restrict__ qg, const float* __restrict__ kg,
    const float* __restrict__ vg, const int* __restrict__ maskg,
    float* __restrict__ outg) {
  __shared__ __bf16 sK[KT][KPITCH];   // K tile, row-major [key][d]   (17408 B)
  __shared__ __bf16 sVT[DH][VPITCH];  // V tile, transposed [d][key]  (18432 B)
  __shared__ __bf16 sP[4][16][PPITCH];  // per-wave P round-trip      (9216 B)

  const int tid = threadIdx.x;
  const int wv = tid >> 6;
  const int ln = tid & 63;
  const int qd = ln >> 4;   // quad 0..3
  const int lc = ln & 15;
  const int bid = blockIdx.x;
  const int b = bid >> 5;
  const int q0 = (bid & 31) << 6;
  const int qw = q0 + (wv << 4);

  // ---- Q fragments (A-layout: A[m=lane&15][k=quad*8+j]), pre-scaled ----
  bf16x8 qf[4];
  {
    const float* qr = qg + ((size_t)(b * QL + qw + lc)) * DH + qd * 8;
#pragma unroll
    for (int kf = 0; kf < 4; ++kf) {
      f32x4 a = *(const f32x4*)(qr + kf * 32);
      f32x4 c = *(const f32x4*)(qr + kf * 32 + 4);
      bf16x8 t;
      t[0] = (__bf16)(a[0] * QSC); t[1] = (__bf16)(a[1] * QSC);
      t[2] = (__bf16)(a[2] * QSC); t[3] = (__bf16)(a[3] * QSC);
      t[4] = (__bf16)(c[0] * QSC); t[5] = (__bf16)(c[1] * QSC);
      t[6] = (__bf16)(c[2] * QSC); t[7] = (__bf16)(c[3] * QSC);
      qf[kf] = t;
    }
  }

  const float* kb = kg + (size_t)b * KLEN * DH;
  const float* vb = vg + (size_t)b * KLEN * DH;
  const int* mrow = maskg + b * KLEN;  // harness widens jax bool -> int32

  // staging registers (prefetch of next tile)
  f32x4 kreg[8], va[4], vbr[4];

  auto load_tile = [&](int t) {
    const float* kt = kb + ((size_t)t * KT) * DH;
#pragma unroll
    for (int it = 0; it < 8; ++it) {
      int f = it * 256 + tid;                     // coalesced float4
      kreg[it] = *(const f32x4*)(kt + (size_t)(f >> 5) * DH + (f & 31) * 4);
    }
    const float* vt = vb + ((size_t)t * KT) * DH;
#pragma unroll
    for (int it = 0; it < 4; ++it) {
      int u = it * 256 + tid;
      int m = u & 31;            // key-pair index (lane-minor: conflict-free LDS writes)
      int dc = (u >> 5) * 4;
      va[it]  = *(const f32x4*)(vt + (size_t)(2 * m) * DH + dc);
      vbr[it] = *(const f32x4*)(vt + (size_t)(2 * m + 1) * DH + dc);
    }
  };

  auto store_tile = [&]() {
#pragma unroll
    for (int it = 0; it < 8; ++it) {
      int f = it * 256 + tid;
      bf16x4 w;
      w[0] = (__bf16)kreg[it][0]; w[1] = (__bf16)kreg[it][1];
      w[2] = (__bf16)kreg[it][2]; w[3] = (__bf16)kreg[it][3];
      *(bf16x4*)&sK[f >> 5][(f & 31) * 4] = w;
    }
#pragma unroll
    for (int it = 0; it < 4; ++it) {
      int u = it * 256 + tid;
      int m = u & 31;
      int dc = (u >> 5) * 4;
#pragma unroll
      for (int j = 0; j < 4; ++j) {
        bf16x2 p2;
        p2[0] = (__bf16)va[it][j];
        p2[1] = (__bf16)vbr[it][j];
        *(bf16x2*)&sVT[dc + j][2 * m] = p2;  // packed b32, lane-consecutive banks
      }
    }
  };

  f32x4 oacc[8];
#pragma unroll
  for (int i = 0; i < 8; ++i) oacc[i] = (f32x4){0.f, 0.f, 0.f, 0.f};
  float mi[4] = {-INFINITY, -INFINITY, -INFINITY, -INFINITY};
  float li[4] = {0.f, 0.f, 0.f, 0.f};

  load_tile(0);
  store_tile();
  __syncthreads();

  for (int t = 0; t < NTILES; ++t) {
    const bool more = (t + 1 < NTILES);
    if (more) load_tile(t + 1);  // in flight during compute

    // ---- S = (Q*QSC) K^T : 4 col-tiles x 4 k-steps, fp32 accum ----
    f32x4 sa[4];
#pragma unroll
    for (int f = 0; f < 4; ++f) sa[f] = (f32x4){0.f, 0.f, 0.f, 0.f};
#pragma unroll
    for (int kf = 0; kf < 4; ++kf) {
#pragma unroll
      for (int f = 0; f < 4; ++f) {
        bf16x8 bk = *(const bf16x8*)&sK[f * 16 + lc][kf * 32 + qd * 8];
        sa[f] = __builtin_amdgcn_mfma_f32_16x16x32_bf16(qf[kf], bk, sa[f], 0, 0, 0);
      }
    }

    // ---- key-padding mask (per-lane key = kv0 + 16f + lc) ----
    const int kv0 = t * KT;
#pragma unroll
    for (int f = 0; f < 4; ++f) {
      const bool keep = mrow[kv0 + f * 16 + lc] != 0;
#pragma unroll
      for (int r = 0; r < 4; ++r) sa[f][r] = keep ? sa[f][r] : NEGV;
    }

    // ---- online softmax (rows live in quad: row = qd*4 + r) ----
    float rm[4], alpha[4], rs[4];
#pragma unroll
    for (int r = 0; r < 4; ++r)
      rm[r] = fmaxf(fmaxf(sa[0][r], sa[1][r]), fmaxf(sa[2][r], sa[3][r]));
#pragma unroll
    for (int s = 0; s < 4; ++s) {
      const int off = 1 << s;  // butterfly over the 16 column lanes
#pragma unroll
      for (int r = 0; r < 4; ++r)
        rm[r] = fmaxf(rm[r], __shfl_xor(rm[r], off, 64));
    }
#pragma unroll
    for (int r = 0; r < 4; ++r) {
      float mn = fmaxf(mi[r], rm[r]);
      alpha[r] = __builtin_amdgcn_exp2f(mi[r] - mn);  // log2 units
      mi[r] = mn;
      rs[r] = 0.f;
    }
#pragma unroll
    for (int f = 0; f < 4; ++f) {
#pragma unroll
      for (int r = 0; r < 4; ++r) {
        float p = __builtin_amdgcn_exp2f(sa[f][r] - mi[r]);
        sa[f][r] = p;
        rs[r] += p;
      }
    }
#pragma unroll
    for (int s = 0; s < 4; ++s) {
      const int off = 1 << s;
#pragma unroll
      for (int r = 0; r < 4; ++r) rs[r] += __shfl_xor(rs[r], off, 64);
    }
#pragma unroll
    for (int r = 0; r < 4; ++r) li[r] = li[r] * alpha[r] + rs[r];

    // ---- P: C-layout -> LDS -> A-layout; rescale O ----
#pragma unroll
    for (int f = 0; f < 4; ++f)
#pragma unroll
      for (int r = 0; r < 4; ++r)
        sP[wv][qd * 4 + r][f * 16 + lc] = (__bf16)sa[f][r];
#pragma unroll
    for (int nt = 0; nt < 8; ++nt)
#pragma unroll
      for (int r = 0; r < 4; ++r) oacc[nt][r] *= alpha[r];

    // ---- O += P V : 8 d-tiles x 2 k-steps ----
#pragma unroll
    for (int kp = 0; kp < 2; ++kp) {
      bf16x8 ap = *(const bf16x8*)&sP[wv][lc][kp * 32 + qd * 8];
#pragma unroll
      for (int nt = 0; nt < 8; ++nt) {
        bf16x8 bv = *(const bf16x8*)&sVT[nt * 16 + lc][kp * 32 + qd * 8];
        oacc[nt] = __builtin_amdgcn_mfma_f32_16x16x32_bf16(ap, bv, oacc[nt], 0, 0, 0);
      }
    }

    __syncthreads();           // everyone done reading sK/sVT
    if (more) store_tile();    // write prefetched tile t+1
    __syncthreads();
  }

  // ---- epilogue: O / l ----
  float inv[4];
#pragma unroll
  for (int r = 0; r < 4; ++r) inv[r] = 1.0f / li[r];
  float* orow = outg + ((size_t)(b * QL + qw)) * DH;
#pragma unroll
  for (int nt = 0; nt < 8; ++nt)
#pragma unroll
    for (int r = 0; r < 4; ++r)
      orow[(size_t)(qd * 4 + r) * DH + nt * 16 + lc] = oacc[nt][r] * inv[r];
}

extern "C" void kernel_launch(void* const* d_in, const int* in_sizes, int n_in,
                              void* d_out, int out_size, void* d_ws, size_t ws_size,
                              hipStream_t stream) {
  (void)in_sizes; (void)n_in; (void)out_size; (void)d_ws; (void)ws_size;
  const float* q = (const float*)d_in[0];
  const float* k = (const float*)d_in[1];
  const float* v = (const float*)d_in[2];
  const int* mask = (const int*)d_in[3];  // harness widens bool -> int32
  float* out = (float*)d_out;
  fattn_kernel<<<dim3(BZ * (QL / 64)), dim3(256), 0, stream>>>(q, k, v, mask, out);
}